// Round 8
// baseline (114.873 us; speedup 1.0000x reference)
//
#include <hip/hip_runtime.h>
#include <hip/hip_bf16.h>

#define D_S 128

typedef short bf16x8 __attribute__((ext_vector_type(8)));
typedef float f32x4 __attribute__((ext_vector_type(4)));

__device__ __forceinline__ unsigned short f32_to_bf16(float f) {
  unsigned int u = __float_as_uint(f);
  return (unsigned short)((u + 0x7FFFu + ((u >> 16) & 1u)) >> 16);  // RN-even
}
__device__ __forceinline__ unsigned int pack2_bf16(float lo, float hi) {
  return (unsigned int)f32_to_bf16(lo) | ((unsigned int)f32_to_bf16(hi) << 16);
}
__device__ __forceinline__ bf16x8 cvt_frag(float4 x, float4 y) {
  union { bf16x8 v; unsigned int u[4]; } r;
  r.u[0] = pack2_bf16(x.x, x.y);
  r.u[1] = pack2_bf16(x.z, x.w);
  r.u[2] = pack2_bf16(y.x, y.y);
  r.u[3] = pack2_bf16(y.z, y.w);
  return r.v;
}

// ---------------------------------------------------------------------------
// Kernel 1 (MFMA, LDS-staged) — unchanged from R7 (passed, ~16us, clean
// writes). Computes AB[n][j] = Wc[j].s[n] (+b1, j<128) in XCD-sliced layout:
//   Atab[(sl*N + n)*16 + i] = AB[n][sl*16 + i]
//   Btab[(sl*N + n)*16 + i] = AB[n][128 + sl*16 + i]
// ---------------------------------------------------------------------------
__global__ __launch_bounds__(256) void precompute_mfma(
    const float* __restrict__ s, const float* __restrict__ W1,
    const float* __restrict__ b1, unsigned short* __restrict__ Atab,
    unsigned short* __restrict__ Btab, int n_nodes) {
  __shared__ __align__(16) unsigned short s_tile[64 * 128];  // 16 KB, swizzled
  __shared__ __align__(16) unsigned short o_tile[64 * 256];  // 32 KB, swizzled
  int t = threadIdx.x;
  int wv = t >> 6, lane = t & 63;
  int lr = lane & 15, lc = lane >> 4;
  int n0 = blockIdx.x * 64;

  // ---- stage s: 64 rows x 128 f32 -> bf16 LDS (coalesced 32B/thread) ----
#pragma unroll
  for (int rep = 0; rep < 4; ++rep) {
    int idx = t + rep * 256;  // 1024 chunks of 8 floats
    int row = idx >> 4;
    int c8 = (idx & 15) * 8;
    int gn = n0 + row;
    if (gn > n_nodes - 1) gn = n_nodes - 1;  // clamp; masked at store
    const float* sp = s + (size_t)gn * D_S + c8;
    float4 x = *(const float4*)sp;
    float4 y = *(const float4*)(sp + 4);
    bf16x8 pk = cvt_frag(x, y);
    int byte = (row * 256 + c8 * 2) ^ ((row & 7) << 4);
    *(bf16x8*)((char*)s_tile + byte) = pk;
  }
  __syncthreads();

  // ---- A fragments from LDS ----
  bf16x8 afrag[4][4];
#pragma unroll
  for (int m = 0; m < 4; ++m) {
    int row = m * 16 + lr;
    int swz = (row & 7) << 4;
#pragma unroll
    for (int ks = 0; ks < 4; ++ks) {
      int byte = (row * 256 + lc * 16 + ks * 64) ^ swz;
      afrag[m][ks] = *(const bf16x8*)((const char*)s_tile + byte);
    }
  }

#pragma unroll 1
  for (int chunk = 0; chunk < 2; ++chunk) {
    bf16x8 bfr[2][4];
#pragma unroll
    for (int nt = 0; nt < 2; ++nt) {
      const float* wrow =
          W1 + (size_t)(wv * 32 + nt * 16 + lr) * (2 * D_S) + chunk * D_S + lc * 8;
#pragma unroll
      for (int ks = 0; ks < 4; ++ks) {
        float4 x = *(const float4*)(wrow + ks * 32);
        float4 y = *(const float4*)(wrow + ks * 32 + 4);
        bfr[nt][ks] = cvt_frag(x, y);
      }
    }

    f32x4 acc[4][2] = {};
#pragma unroll
    for (int ks = 0; ks < 4; ++ks)
#pragma unroll
      for (int m = 0; m < 4; ++m)
#pragma unroll
        for (int nt = 0; nt < 2; ++nt)
          acc[m][nt] = __builtin_amdgcn_mfma_f32_16x16x32_bf16(
              afrag[m][ks], bfr[nt][ks], acc[m][nt], 0, 0, 0);

    if (chunk == 0) {
#pragma unroll
      for (int nt = 0; nt < 2; ++nt) {
        float bv = b1[wv * 32 + nt * 16 + lr];
#pragma unroll
        for (int m = 0; m < 4; ++m)
#pragma unroll
          for (int r = 0; r < 4; ++r) acc[m][nt][r] += bv;
      }
    }

#pragma unroll
    for (int m = 0; m < 4; ++m)
#pragma unroll
      for (int nt = 0; nt < 2; ++nt) {
        int col = chunk * 128 + wv * 32 + nt * 16 + lr;
#pragma unroll
        for (int r = 0; r < 4; ++r) {
          int row = m * 16 + lc * 4 + r;
          int byte = (row * 512 + col * 2) ^ ((row & 7) << 4);
          *(unsigned short*)((char*)o_tile + byte) = f32_to_bf16(acc[m][nt][r]);
        }
      }
  }
  __syncthreads();

#pragma unroll
  for (int rep = 0; rep < 2; ++rep) {
    int idx = t + rep * 256;  // 512 = 8 slices x 64 nodes
    int sl = idx >> 6, node = idx & 63;
    int gn = n0 + node;
    if (gn < n_nodes) {
      int sw = (node & 7) << 4;
      int base = node * 512 + sl * 32;
      uint4 ra0 = *(const uint4*)((const char*)o_tile + ((base) ^ sw));
      uint4 ra1 = *(const uint4*)((const char*)o_tile + ((base + 16) ^ sw));
      uint4 rb0 = *(const uint4*)((const char*)o_tile + ((base + 256) ^ sw));
      uint4 rb1 = *(const uint4*)((const char*)o_tile + ((base + 256 + 16) ^ sw));
      size_t rec = ((size_t)sl * n_nodes + gn) << 4;
      *(uint4*)(Atab + rec) = ra0;
      *(uint4*)(Atab + rec + 8) = ra1;
      *(uint4*)(Btab + rec) = rb0;
      *(uint4*)(Btab + rec + 8) = rb1;
    }
  }
}

// ---------------------------------------------------------------------------
// Kernel 2: XCD-sliced edge gather, PAIR-LANE version.
// slice = blockIdx%8 (round-robin -> one XCD per slice; slice tables
// 1.6+1.6 MB fit its 4MB L2 — validated by R7's FETCH collapse 176->37MB).
// R7 bug fixed: each 32B record was read by 2 instrs x 64 divergent lanes
// = 2 L2 requests/record -> request-rate wall (~42us). Now lane 2p and
// lane 2p+1 read the two contiguous 16B halves of the SAME record -> the
// coalescer merges them into 1 request/record (16 req/edge instead of 32).
// Each lane does silu over its 8 k; pair combines via shfl_xor(p,1).
// 4 edges per pair (512/block): 8 independent gathers in flight per lane.
// ---------------------------------------------------------------------------
__device__ __forceinline__ float silu2(unsigned int ua, unsigned int ub,
                                       float wlo, float whi) {
  float h0 = __uint_as_float(ua << 16) + __uint_as_float(ub << 16);
  float h1 = __uint_as_float(ua & 0xFFFF0000u) + __uint_as_float(ub & 0xFFFF0000u);
  float e0 = __builtin_amdgcn_exp2f(h0 * -1.442695041f);
  float e1 = __builtin_amdgcn_exp2f(h1 * -1.442695041f);
  float r0 = __builtin_amdgcn_rcpf(1.f + e0);
  float r1 = __builtin_amdgcn_rcpf(1.f + e1);
  return h0 * r0 * wlo + h1 * r1 * whi;
}

__global__ __launch_bounds__(256) void edge_sliced(
    const int* __restrict__ ei, const unsigned short* __restrict__ Atab,
    const unsigned short* __restrict__ Btab, const float* __restrict__ W2,
    float* __restrict__ P, int E, int N) {
  int t = threadIdx.x;
  int slice = blockIdx.x & 7;
  int base = (blockIdx.x >> 3) * 512;
  int p = t >> 1;      // pair id 0..127
  int half = t & 1;    // which 16B half of the 32B record

  const float4* wp = (const float4*)(W2 + (slice << 4) + (half << 3));
  float4 w0 = wp[0], w1 = wp[1];
  size_t slN = (size_t)slice * N;

  int e[4];
  int row[4], col[4];
#pragma unroll
  for (int r = 0; r < 4; ++r) {
    int ee = base + r * 128 + p;
    if (ee >= E) ee = E - 1;  // duplicate tail: same value written, benign
    e[r] = ee;
    row[r] = __builtin_nontemporal_load(ei + ee);
    col[r] = __builtin_nontemporal_load(ei + E + ee);
  }

  uint4 av[4], bv[4];
#pragma unroll
  for (int r = 0; r < 4; ++r) {
    av[r] = *((const uint4*)(Atab + ((slN + row[r]) << 4)) + half);
    bv[r] = *((const uint4*)(Btab + ((slN + col[r]) << 4)) + half);
  }

#pragma unroll
  for (int r = 0; r < 4; ++r) {
    float pp = silu2(av[r].x, bv[r].x, w0.x, w0.y) +
               silu2(av[r].y, bv[r].y, w0.z, w0.w) +
               silu2(av[r].z, bv[r].z, w1.x, w1.y) +
               silu2(av[r].w, bv[r].w, w1.z, w1.w);
    pp += __shfl_xor(pp, 1, 64);  // combine the two record-halves
    if (half == 0)
      __builtin_nontemporal_store(pp, P + (size_t)slice * E + e[r]);
  }
}

// ---------------------------------------------------------------------------
// Kernel 3: out[e] = b2 + sum_sl P[sl][e]  (fixed order: deterministic).
// float4 per thread; 8 coalesced nontemporal stream reads.
// ---------------------------------------------------------------------------
__global__ __launch_bounds__(256) void combine(
    const float* __restrict__ P, const float* __restrict__ b2,
    float* __restrict__ out, int E) {
  int i4 = blockIdx.x * 256 + threadIdx.x;
  int n4 = E >> 2;
  if (i4 < n4) {
    float bb = b2[0];
    float4 v = make_float4(bb, bb, bb, bb);
#pragma unroll
    for (int k = 0; k < 8; ++k) {
      const float4* pk = (const float4*)(P + (size_t)k * E);
      float4 q = pk[i4];
      v.x += q.x; v.y += q.y; v.z += q.z; v.w += q.w;
    }
    ((float4*)out)[i4] = v;
  }
  // scalar tail (E % 4)
  if (blockIdx.x == 0 && threadIdx.x < (E & 3)) {
    int e = (E & ~3) + threadIdx.x;
    float v = b2[0];
#pragma unroll
    for (int k = 0; k < 8; ++k) v += P[(size_t)k * E + e];
    out[e] = v;
  }
}

// ---------------------------------------------------------------------------
// Fallback (workspace too small): direct per-edge compute, fp32.
// ---------------------------------------------------------------------------
__global__ __launch_bounds__(256) void edge_direct(
    const float* __restrict__ s, const int* __restrict__ ei,
    const float* __restrict__ W1, const float* __restrict__ b1,
    const float* __restrict__ W2, const float* __restrict__ b2,
    float* __restrict__ out, int E) {
  __shared__ float sh[256];
  __shared__ float red[128];
  int e = blockIdx.x;
  int t = threadIdx.x;
  int row = ei[e], col = ei[E + e];
  sh[t] = (t < 128) ? s[(size_t)row * D_S + t] : s[(size_t)col * D_S + (t - 128)];
  __syncthreads();
  if (t < 128) {
    float acc = b1[t];
    const float* w = W1 + (size_t)t * 256;
#pragma unroll 8
    for (int jj = 0; jj < 256; ++jj) acc += sh[jj] * w[jj];
    red[t] = (acc / (1.f + __expf(-acc))) * W2[t];
  }
  __syncthreads();
  if (t < 64) {
    float x = red[t] + red[t + 64];
#pragma unroll
    for (int off = 32; off; off >>= 1) x += __shfl_xor(x, off, 64);
    if (t == 0) out[e] = x + b2[0];
  }
}

extern "C" void kernel_launch(void* const* d_in, const int* in_sizes, int n_in,
                              void* d_out, int out_size, void* d_ws, size_t ws_size,
                              hipStream_t stream) {
  const float* s  = (const float*)d_in[0];
  const int*   ei = (const int*)d_in[1];
  const float* W1 = (const float*)d_in[2];
  const float* b1 = (const float*)d_in[3];
  const float* W2 = (const float*)d_in[4];
  const float* b2 = (const float*)d_in[5];
  float* out = (float*)d_out;

  int n_nodes = in_sizes[0] / D_S;
  int E = in_sizes[1] / 2;

  size_t tab_elems = (size_t)8 * n_nodes * 16;              // per table, ushort
  size_t need = 2 * tab_elems * sizeof(unsigned short) +    // Atab + Btab
                (size_t)8 * E * sizeof(float);              // P partials
  if (ws_size >= need) {
    unsigned short* Atab = (unsigned short*)d_ws;
    unsigned short* Btab = Atab + tab_elems;
    float* P = (float*)(Btab + tab_elems);
    precompute_mfma<<<(n_nodes + 63) / 64, 256, 0, stream>>>(s, W1, b1, Atab,
                                                             Btab, n_nodes);
    int bps = (E + 511) / 512;  // blocks per slice
    edge_sliced<<<bps * 8, 256, 0, stream>>>(ei, Atab, Btab, W2, P, E,
                                             n_nodes);
    combine<<<(E / 4 + 255) / 256, 256, 0, stream>>>(P, b2, out, E);
  } else {
    edge_direct<<<E, 256, 0, stream>>>(s, ei, W1, b1, W2, b2, out, E);
  }
}

// Round 9
// 81.904 us; speedup vs baseline: 1.4025x; 1.4025x over previous
//
#include <hip/hip_runtime.h>
#include <hip/hip_bf16.h>

#define D_S 128

typedef short bf16x8 __attribute__((ext_vector_type(8)));
typedef float f32x4 __attribute__((ext_vector_type(4)));

__device__ __forceinline__ unsigned short f32_to_bf16(float f) {
  unsigned int u = __float_as_uint(f);
  return (unsigned short)((u + 0x7FFFu + ((u >> 16) & 1u)) >> 16);  // RN-even
}
__device__ __forceinline__ unsigned int pack2_bf16(float lo, float hi) {
  return (unsigned int)f32_to_bf16(lo) | ((unsigned int)f32_to_bf16(hi) << 16);
}
__device__ __forceinline__ bf16x8 cvt_frag(float4 x, float4 y) {
  union { bf16x8 v; unsigned int u[4]; } r;
  r.u[0] = pack2_bf16(x.x, x.y);
  r.u[1] = pack2_bf16(x.z, x.w);
  r.u[2] = pack2_bf16(y.x, y.y);
  r.u[3] = pack2_bf16(y.z, y.w);
  return r.v;
}

// ---------------------------------------------------------------------------
// Kernel 1 (MFMA, LDS-staged): AB[n][j] = Wc[j].s[n] (+b1[j] for j<128),
// bf16, INTERLEAVED layout (AB[n][0:128]=A-half, AB[n][128:256]=B-half).
// Block = 256 thr (4 waves), tile 64 nodes x 256 j, K=128.
// s staged coalesced -> XOR-swizzled LDS; A-frags from LDS; B-frags from W1
// fp32 (L2-hot 128KB) with in-register cvt. D layout (m89): col=lane&15,
// row=(lane>>4)*4+reg. Output bounced via swizzled o_tile -> 32B/thread
// contiguous global stores.
// History: R7/R8 sliced-output variant of this kernel worked but the sliced
// EDGE design lost to fabric-efficient interleaved gathers; this is the
// R7 core emitting the R5 layout, with no extra w1cvt/combine launches.
// ---------------------------------------------------------------------------
__global__ __launch_bounds__(256) void precompute_mfma(
    const float* __restrict__ s, const float* __restrict__ W1,
    const float* __restrict__ b1, unsigned short* __restrict__ AB,
    int n_nodes) {
  __shared__ __align__(16) unsigned short s_tile[64 * 128];  // 16 KB, swizzled
  __shared__ __align__(16) unsigned short o_tile[64 * 256];  // 32 KB, swizzled
  int t = threadIdx.x;
  int wv = t >> 6, lane = t & 63;
  int lr = lane & 15, lc = lane >> 4;
  int n0 = blockIdx.x * 64;

  // ---- stage s: 64 rows x 128 f32 -> bf16 LDS (coalesced 32B/thread) ----
#pragma unroll
  for (int rep = 0; rep < 4; ++rep) {
    int idx = t + rep * 256;  // 1024 chunks of 8 floats
    int row = idx >> 4;
    int c8 = (idx & 15) * 8;
    int gn = n0 + row;
    if (gn > n_nodes - 1) gn = n_nodes - 1;  // clamp; masked at store
    const float* sp = s + (size_t)gn * D_S + c8;
    float4 x = *(const float4*)sp;
    float4 y = *(const float4*)(sp + 4);
    bf16x8 pk = cvt_frag(x, y);
    int byte = (row * 256 + c8 * 2) ^ ((row & 7) << 4);
    *(bf16x8*)((char*)s_tile + byte) = pk;
  }
  __syncthreads();

  // ---- A fragments from LDS ----
  bf16x8 afrag[4][4];
#pragma unroll
  for (int m = 0; m < 4; ++m) {
    int row = m * 16 + lr;
    int swz = (row & 7) << 4;
#pragma unroll
    for (int ks = 0; ks < 4; ++ks) {
      int byte = (row * 256 + lc * 16 + ks * 64) ^ swz;
      afrag[m][ks] = *(const bf16x8*)((const char*)s_tile + byte);
    }
  }

#pragma unroll 1
  for (int chunk = 0; chunk < 2; ++chunk) {
    // B fragments: Wc row j = chunk*128 + wv*32 + nt*16 + lr
    //   -> W1[j - chunk*128][chunk*128 + k]
    bf16x8 bfr[2][4];
#pragma unroll
    for (int nt = 0; nt < 2; ++nt) {
      const float* wrow =
          W1 + (size_t)(wv * 32 + nt * 16 + lr) * (2 * D_S) + chunk * D_S + lc * 8;
#pragma unroll
      for (int ks = 0; ks < 4; ++ks) {
        float4 x = *(const float4*)(wrow + ks * 32);
        float4 y = *(const float4*)(wrow + ks * 32 + 4);
        bfr[nt][ks] = cvt_frag(x, y);
      }
    }

    f32x4 acc[4][2] = {};
#pragma unroll
    for (int ks = 0; ks < 4; ++ks)
#pragma unroll
      for (int m = 0; m < 4; ++m)
#pragma unroll
        for (int nt = 0; nt < 2; ++nt)
          acc[m][nt] = __builtin_amdgcn_mfma_f32_16x16x32_bf16(
              afrag[m][ks], bfr[nt][ks], acc[m][nt], 0, 0, 0);

    if (chunk == 0) {  // bias on the A half only
#pragma unroll
      for (int nt = 0; nt < 2; ++nt) {
        float bv = b1[wv * 32 + nt * 16 + lr];
#pragma unroll
        for (int m = 0; m < 4; ++m)
#pragma unroll
          for (int r = 0; r < 4; ++r) acc[m][nt][r] += bv;
      }
    }

    // pack D -> o_tile (2B stores, swizzled; R7 measured 0 bank conflicts)
#pragma unroll
    for (int m = 0; m < 4; ++m)
#pragma unroll
      for (int nt = 0; nt < 2; ++nt) {
        int col = chunk * 128 + wv * 32 + nt * 16 + lr;
#pragma unroll
        for (int r = 0; r < 4; ++r) {
          int row = m * 16 + lc * 4 + r;
          int byte = (row * 512 + col * 2) ^ ((row & 7) << 4);
          *(unsigned short*)((char*)o_tile + byte) = f32_to_bf16(acc[m][nt][r]);
        }
      }
  }
  __syncthreads();

  // ---- interleaved copy-out: idx -> (node, 16-j group), 32B contiguous ----
#pragma unroll
  for (int rep = 0; rep < 4; ++rep) {
    int idx = t + rep * 256;  // 1024 = 64 nodes x 16 j-groups
    int node = idx >> 4, jg = idx & 15;
    int gn = n0 + node;
    if (gn < n_nodes) {
      int sw = (node & 7) << 4;
      int base = node * 512 + jg * 32;
      uint4 v0 = *(const uint4*)((const char*)o_tile + (base ^ sw));
      uint4 v1 = *(const uint4*)((const char*)o_tile + ((base + 16) ^ sw));
      unsigned short* dst = AB + (size_t)gn * 256 + jg * 16;
      *(uint4*)dst = v0;
      *(uint4*)(dst + 8) = v1;
    }
  }
}

// ---------------------------------------------------------------------------
// Kernel 2: per-edge gather (R5 design, measured 53.0us = the ~3.4TB/s
// fabric-path ceiling for this random-line pattern; R7/R8 L2-resident sliced
// variants were SLOWER due to fine-grained request inefficiency).
// 8 edges/wave, 8 lanes/edge, 16 k/lane:
//   out[e] = sum_k W2[k] * silu(A[row][k] + B[col][k]) + b2
// Per lane: 2x dwordx4 per half-row (8 lanes x 32B = 256B = one half-row,
// fully coalesced, every fetched 64B line fully consumed). 3-step shfl
// reduce; 32-bit voffsets; raw v_exp/v_rcp.
// ---------------------------------------------------------------------------
__device__ __forceinline__ float silu2(unsigned int ua, unsigned int ub,
                                       float wlo, float whi) {
  float h0 = __uint_as_float(ua << 16) + __uint_as_float(ub << 16);
  float h1 = __uint_as_float(ua & 0xFFFF0000u) + __uint_as_float(ub & 0xFFFF0000u);
  float e0 = __builtin_amdgcn_exp2f(h0 * -1.442695041f);
  float e1 = __builtin_amdgcn_exp2f(h1 * -1.442695041f);
  float r0 = __builtin_amdgcn_rcpf(1.f + e0);
  float r1 = __builtin_amdgcn_rcpf(1.f + e1);
  return h0 * r0 * wlo + h1 * r1 * whi;
}

__global__ __launch_bounds__(256) void edge_kernel(
    const int* __restrict__ ei, const unsigned short* __restrict__ AB,
    const float* __restrict__ W2, const float* __restrict__ b2,
    float* __restrict__ out, int E) {
  int t = threadIdx.x;
  int wv = (blockIdx.x << 2) + (t >> 6);
  int lane = t & 63;
  int g = lane >> 3, sub = lane & 7;
  int e = wv * 8 + g;
  if (e >= E) e = E - 1;  // duplicate tail edge: deterministic, same value

  int row = ei[e];
  int col = ei[E + e];

  unsigned int sh = (unsigned int)(sub << 4);
  unsigned int offA = ((unsigned int)row << 8) + sh;
  unsigned int offB = ((unsigned int)col << 8) + 128 + sh;
  uint4 a0 = *(const uint4*)(AB + offA);
  uint4 a1 = *(const uint4*)(AB + offA + 8);
  uint4 b0 = *(const uint4*)(AB + offB);
  uint4 b1v = *(const uint4*)(AB + offB + 8);

  const float4* wp = (const float4*)(W2 + (sub << 4));
  float4 w0 = wp[0], w1 = wp[1], w2 = wp[2], w3 = wp[3];

  float p = 0.f;
  p += silu2(a0.x, b0.x, w0.x, w0.y);
  p += silu2(a0.y, b0.y, w0.z, w0.w);
  p += silu2(a0.z, b0.z, w1.x, w1.y);
  p += silu2(a0.w, b0.w, w1.z, w1.w);
  p += silu2(a1.x, b1v.x, w2.x, w2.y);
  p += silu2(a1.y, b1v.y, w2.z, w2.w);
  p += silu2(a1.z, b1v.z, w3.x, w3.y);
  p += silu2(a1.w, b1v.w, w3.z, w3.w);

#pragma unroll
  for (int off = 1; off < 8; off <<= 1) p += __shfl_xor(p, off, 64);

  if (sub == 0) out[e] = p + b2[0];
}

// ---------------------------------------------------------------------------
// Fallback (workspace too small): direct per-edge compute, fp32.
// ---------------------------------------------------------------------------
__global__ __launch_bounds__(256) void edge_direct(
    const float* __restrict__ s, const int* __restrict__ ei,
    const float* __restrict__ W1, const float* __restrict__ b1,
    const float* __restrict__ W2, const float* __restrict__ b2,
    float* __restrict__ out, int E) {
  __shared__ float sh[256];
  __shared__ float red[128];
  int e = blockIdx.x;
  int t = threadIdx.x;
  int row = ei[e], col = ei[E + e];
  sh[t] = (t < 128) ? s[(size_t)row * D_S + t] : s[(size_t)col * D_S + (t - 128)];
  __syncthreads();
  if (t < 128) {
    float acc = b1[t];
    const float* w = W1 + (size_t)t * 256;
#pragma unroll 8
    for (int jj = 0; jj < 256; ++jj) acc += sh[jj] * w[jj];
    red[t] = (acc / (1.f + __expf(-acc))) * W2[t];
  }
  __syncthreads();
  if (t < 64) {
    float x = red[t] + red[t + 64];
#pragma unroll
    for (int off = 32; off; off >>= 1) x += __shfl_xor(x, off, 64);
    if (t == 0) out[e] = x + b2[0];
  }
}

extern "C" void kernel_launch(void* const* d_in, const int* in_sizes, int n_in,
                              void* d_out, int out_size, void* d_ws, size_t ws_size,
                              hipStream_t stream) {
  const float* s  = (const float*)d_in[0];
  const int*   ei = (const int*)d_in[1];
  const float* W1 = (const float*)d_in[2];
  const float* b1 = (const float*)d_in[3];
  const float* W2 = (const float*)d_in[4];
  const float* b2 = (const float*)d_in[5];
  float* out = (float*)d_out;

  int n_nodes = in_sizes[0] / D_S;
  int E = in_sizes[1] / 2;

  size_t need = (size_t)n_nodes * 256 * sizeof(unsigned short);
  if (ws_size >= need) {
    unsigned short* AB = (unsigned short*)d_ws;
    precompute_mfma<<<(n_nodes + 63) / 64, 256, 0, stream>>>(s, W1, b1, AB,
                                                             n_nodes);
    int blocks = (E + 31) / 32;  // 4 waves/block, 8 edges/wave
    edge_kernel<<<blocks, 256, 0, stream>>>(ei, AB, W2, b2, out, E);
  } else {
    edge_direct<<<E, 256, 0, stream>>>(s, ei, W1, b1, W2, b2, out, E);
  }
}